// Round 4
// baseline (43.212 us; speedup 1.0000x reference)
//
#include <hip/hip_runtime.h>

#define SENT (-3.402823466e38f)

__device__ __forceinline__ float dot4(float4 a, float4 b) {
    return a.x*b.x + a.y*b.y + a.z*b.z + a.w*b.w;
}

// One block per 2 rows (b,i). 512 threads = 8 waves. Everything fused:
// q/vnode/qkp projections -> logits -> softmax -> edge agg -> y -> out proj.
// Weight matrices are streamed from L2 per block; 2-row batching halves traffic.
__global__ __launch_bounds__(512, 1)
void fused_all(const float* __restrict__ x, const int* __restrict__ msk,
               const float* __restrict__ edge,
               const float* __restrict__ Wq, const float* __restrict__ bq,
               const float* __restrict__ Wk,
               const float* __restrict__ Wv, const float* __restrict__ bv,
               const float* __restrict__ Wp, const float* __restrict__ bp,
               float* __restrict__ out) {
    __shared__ float eds[2][128*68];   // edge rows, stride 68 (16B-aligned rows)
    __shared__ float xL[2][256];
    __shared__ float qls[2][256];      // q = Wq x + bq
    __shared__ float vnodeL[2][256];   // Wv_node x + bv
    __shared__ float qkpL[2][512];     // (q^T Wk_edge) * 1/sqrt(D), [h][e]
    __shared__ float mval[2][128];
    __shared__ float attL[8*132];      // logits -> weights, stride 132
    __shared__ float aggP[1024];       // [jh][h][e] partials
    __shared__ float aggF[2][512];     // per-row final agg [h][e]
    __shared__ float yL[2][256];

    int tid = threadIdx.x;
    int wv = tid >> 6, lane = tid & 63;
    int rA = blockIdx.x * 2;

    {   // load x rows + mask
        int r = tid >> 8, c = tid & 255;
        xL[r][c] = x[(size_t)(rA + r)*256 + c];
        if (tid < 256) {
            int rr = tid >> 7, j = tid & 127;
            mval[rr][j] = (msk[(size_t)(rA + rr)*128 + j] != 0) ? 1.0f : 0.0f;
        }
    }
    __syncthreads();

    // issue edge loads (both rows) into regs -- latency hides under proj loop
    float4 eA[4], eB[4];
    {
        const float* egA = edge + (size_t)rA * 8192;
        const float* egB = egA + 8192;
        #pragma unroll
        for (int it = 0; it < 4; ++it) eA[it] = *(const float4*)(egA + (tid + 512*it)*4);
        #pragma unroll
        for (int it = 0; it < 4; ++it) eB[it] = *(const float4*)(egB + (tid + 512*it)*4);
    }

    {   // q + vnode projections for both rows: thread = (c, half of K)
        int cq = tid >> 1, half = tid & 1;
        const float* wqp = Wq + (size_t)cq*256 + half*128;
        const float* wvp = Wv + (size_t)cq*320 + half*128;
        float aqA=0.f, aqB=0.f, avA=0.f, avB=0.f;
        #pragma unroll 8
        for (int i = 0; i < 32; ++i) {
            float4 w4q = *(const float4*)&wqp[i*4];
            float4 w4v = *(const float4*)&wvp[i*4];
            float4 xa = *(float4*)&xL[0][half*128 + i*4];
            float4 xb = *(float4*)&xL[1][half*128 + i*4];
            aqA += dot4(w4q, xa); aqB += dot4(w4q, xb);
            avA += dot4(w4v, xa); avB += dot4(w4v, xb);
        }
        // stage edge regs -> LDS (loads long since arrived)
        #pragma unroll
        for (int it = 0; it < 4; ++it) {
            int fid = (tid + 512*it)*4;
            int j = fid >> 6, e = fid & 63;
            *(float4*)&eds[0][j*68 + e] = eA[it];
            *(float4*)&eds[1][j*68 + e] = eB[it];
        }
        aqA += __shfl_xor(aqA, 1); aqB += __shfl_xor(aqB, 1);
        avA += __shfl_xor(avA, 1); avB += __shfl_xor(avB, 1);
        if (half == 0) {
            float bqv = bq[cq], bvv = bv[cq];
            qls[0][cq]    = aqA + bqv; qls[1][cq]    = aqB + bqv;
            vnodeL[0][cq] = avA + bvv; vnodeL[1][cq] = avB + bvv;
        }
    }
    __syncthreads();

    {   // qkp: thread = (r, h, e-pair); Wk edge cols coalesced 256B/wave
        int r = tid >> 8, h = (tid >> 5) & 7, e2 = tid & 31;
        const float* wkp = Wk + (size_t)(h*32)*320 + 256 + e2*2;
        float ax = 0.f, ay = 0.f;
        #pragma unroll 8
        for (int d = 0; d < 32; ++d) {
            float qd = qls[r][h*32 + d];           // wave-uniform broadcast
            float2 w2 = *(const float2*)&wkp[(size_t)d*320];
            ax += qd*w2.x; ay += qd*w2.y;
        }
        ax *= 0.17677669529663687f;  // 1/sqrt(32)
        ay *= 0.17677669529663687f;
        qkpL[r][h*64 + e2*2]     = ax;
        qkpL[r][h*64 + e2*2 + 1] = ay;
    }
    __syncthreads();

    #pragma unroll 1
    for (int r = 0; r < 2; ++r) {
        {   // logits: wave = (head-pair, j-half)
            int hp = wv >> 1, jh = wv & 1, h0 = hp*2;
            int j = jh*64 + lane;
            float a0 = 0.f, a1 = 0.f;
            #pragma unroll
            for (int ec = 0; ec < 16; ++ec) {
                float4 ev = *(float4*)&eds[r][j*68 + ec*4];
                float4 qa = *(float4*)&qkpL[r][h0*64 + ec*4];
                float4 qb = *(float4*)&qkpL[r][(h0+1)*64 + ec*4];
                a0 += dot4(ev, qa); a1 += dot4(ev, qb);
            }
            float valid = mval[r][j];
            attL[h0*132 + j]     = (valid > 0.5f) ? a0 : SENT;
            attL[(h0+1)*132 + j] = (valid > 0.5f) ? a1 : SENT;
        }
        __syncthreads();

        {   // softmax: wave wv handles head wv
            float v0 = attL[wv*132 + lane];
            float v1 = attL[wv*132 + 64 + lane];
            float m = fmaxf(v0, v1);
            #pragma unroll
            for (int off = 32; off >= 1; off >>= 1) m = fmaxf(m, __shfl_xor(m, off));
            float e0 = __expf(v0 - m), e1 = __expf(v1 - m);
            float s = e0 + e1;
            #pragma unroll
            for (int off = 32; off >= 1; off >>= 1) s += __shfl_xor(s, off);
            float inv = 1.0f / s;
            attL[wv*132 + lane]      = e0 * inv;
            attL[wv*132 + 64 + lane] = e1 * inv;
        }
        __syncthreads();

        {   // edge agg: wave = (head-pair, j-half); lane = (jj, ec)
            int hp = wv >> 1, jh = wv & 1, h0 = hp*2;
            int jj = lane & 3, ec = lane >> 2;
            float4 a0 = {0,0,0,0}, a1 = {0,0,0,0};
            #pragma unroll
            for (int js = 0; js < 16; ++js) {
                int j = jh*64 + js*4 + jj;
                float4 ev = *(float4*)&eds[r][j*68 + ec*4];
                float w0 = attL[h0*132 + j];
                float w1 = attL[(h0+1)*132 + j];
                a0.x += w0*ev.x; a0.y += w0*ev.y; a0.z += w0*ev.z; a0.w += w0*ev.w;
                a1.x += w1*ev.x; a1.y += w1*ev.y; a1.z += w1*ev.z; a1.w += w1*ev.w;
            }
            #pragma unroll
            for (int off = 1; off <= 2; off <<= 1) {
                a0.x += __shfl_xor(a0.x, off); a0.y += __shfl_xor(a0.y, off);
                a0.z += __shfl_xor(a0.z, off); a0.w += __shfl_xor(a0.w, off);
                a1.x += __shfl_xor(a1.x, off); a1.y += __shfl_xor(a1.y, off);
                a1.z += __shfl_xor(a1.z, off); a1.w += __shfl_xor(a1.w, off);
            }
            if (jj == 0) {
                *(float4*)&aggP[jh*512 + h0*64 + ec*4]     = a0;
                *(float4*)&aggP[jh*512 + (h0+1)*64 + ec*4] = a1;
            }
        }
        __syncthreads();
        aggF[r][tid] = aggP[tid] + aggP[512 + tid];
        __syncthreads();
    }

    {   // y = vnode + agg @ WvE^T, both rows: thread = (r, c)
        int r = tid >> 8, c = tid & 255, h = c >> 5;
        const float* wve = Wv + (size_t)c*320 + 256;
        float acc = vnodeL[r][c];
        #pragma unroll
        for (int ec = 0; ec < 16; ++ec) {
            float4 ag = *(float4*)&aggF[r][h*64 + ec*4];
            float4 w4 = *(const float4*)&wve[ec*4];
            acc += dot4(ag, w4);
        }
        yL[r][c] = acc;
    }
    __syncthreads();

    {   // out projection, both rows: thread = (o, half of K)
        int o = tid >> 1, half = tid & 1;
        const float* wpp = Wp + (size_t)o*256 + half*128;
        float aA = 0.f, aB = 0.f;
        #pragma unroll 8
        for (int i = 0; i < 32; ++i) {
            float4 w4 = *(const float4*)&wpp[i*4];
            float4 ya = *(float4*)&yL[0][half*128 + i*4];
            float4 yb = *(float4*)&yL[1][half*128 + i*4];
            aA += dot4(w4, ya); aB += dot4(w4, yb);
        }
        aA += __shfl_xor(aA, 1); aB += __shfl_xor(aB, 1);
        float bpv = bp[o];
        if (half == 0) out[(size_t)rA*256 + o]       = aA + bpv;
        else           out[(size_t)(rA + 1)*256 + o] = aB + bpv;
    }
}

extern "C" void kernel_launch(void* const* d_in, const int* in_sizes, int n_in,
                              void* d_out, int out_size, void* d_ws, size_t ws_size,
                              hipStream_t stream) {
    (void)in_sizes; (void)n_in; (void)out_size; (void)d_ws; (void)ws_size;
    const float* x    = (const float*)d_in[0];
    // d_in[1] aux_x: unused by reference
    const int*   msk  = (const int*)d_in[2];
    const float* edge = (const float*)d_in[3];
    const float* Wq   = (const float*)d_in[4];
    const float* bq   = (const float*)d_in[5];
    const float* Wk   = (const float*)d_in[6];
    // d_in[7] bk: constant over j -> cancels in softmax, never needed
    const float* Wv   = (const float*)d_in[8];
    const float* bv   = (const float*)d_in[9];
    const float* Wp   = (const float*)d_in[10];
    const float* bp   = (const float*)d_in[11];
    float* out = (float*)d_out;

    fused_all<<<256, 512, 0, stream>>>(x, msk, edge, Wq, bq, Wk, Wv, bv, Wp, bp, out);
}